// Round 7
// baseline (520.260 us; speedup 1.0000x reference)
//
#include <hip/hip_runtime.h>
#include <hip/hip_bf16.h>

// scores[b,t] = sum_u tanh((source@W1)[b,u] + (target@W2)[b,t,u]) * a[u]
// B=64 T=8192 D=256 U=128. Memory-bound: 537MB target read; ~86us floor at 6.3TB/s.
// Round 7: barrier-free linear staging. R6's idea (row-linear loads for DRAM page
// locality) was right but its structure serialized (2 barriers/tile, vmcnt(0) at
// every tile head, depth-1 staging). Now: per-WAVE private LDS slot (16 rows x
// half-k bf16, 4.3KB), wave computes all 128 u for its own rows -> no cross-wave
// deps, ZERO barriers in main loop. Loads are full 512B row-halves in lane order.
// W2 in LDS (R4 layout). 1 block/CU x 1024 thr, LDS 142KB, ~100 VGPR.

#define B_ 64
#define T_ 8192
#define D_ 256
#define U_ 128
#define W2S 264      // W2 LDS stride (bf16): 528B = 33*16 -> aligned, 2-way banks
#define SLS 136      // slot stride (bf16): 272B = 17*16 -> aligned, 2-way banks

typedef __attribute__((ext_vector_type(8))) short bf16x8;
typedef __attribute__((ext_vector_type(4))) short bf16x4;
typedef __attribute__((ext_vector_type(4))) float f32x4;

__device__ __forceinline__ short f2bf(float f) {
    unsigned u = __builtin_bit_cast(unsigned, f);
    u += 0x7fffu + ((u >> 16) & 1u);   // RTNE
    return (short)(u >> 16);
}

__device__ __forceinline__ float fast_tanh(float x) {
    float e = __expf(2.0f * x);
    return 1.0f - 2.0f * __builtin_amdgcn_rcpf(e + 1.0f);
}

__device__ __forceinline__ bf16x4 cvt4(const float4& a) {
    union { __hip_bfloat162 h[2]; bf16x4 v; } u;
    u.h[0] = __float22bfloat162_rn(make_float2(a.x, a.y));
    u.h[1] = __float22bfloat162_rn(make_float2(a.z, a.w));
    return u.v;
}

__global__ __launch_bounds__(1024)
__attribute__((amdgpu_waves_per_eu(4, 4)))
void additive_attn_kernel(
        const float* __restrict__ target,
        const float* __restrict__ source,
        const float* __restrict__ W1,
        const float* __restrict__ W2,
        const float* __restrict__ attn,
        float* __restrict__ out) {
    __shared__ __attribute__((aligned(16))) short lds_w2[U_ * W2S];      // 67584 B
    __shared__ __attribute__((aligned(16))) short lds_slot[16][16 * SLS];// 69632 B
    __shared__ float  lds_red[1024];                                     // 4096 B
    __shared__ __attribute__((aligned(16))) float2 lds_sa[U_];           // 1024 B

    const int tid  = threadIdx.x;
    const int bx   = blockIdx.x;
    const int b    = bx >> 2;            // 4 blocks per batch element
    const int tb   = (bx & 3) << 11;     // 2048 rows per block

    const int lane = tid & 63;
    const int wave = tid >> 6;           // 0..15; each wave owns 128 rows
    const int c    = lane & 15;
    const int g    = lane >> 4;
    const int lrow = lane >> 5;          // row parity for staging loads
    const int lcol = (lane & 31) * 4;    // fp32 col within a 512B row-half

    const float* wtgt = target + ((size_t)b * T_ + tb + wave * 128) * D_;
    float*       wout = out + (size_t)b * T_ + tb + wave * 128;
    short*       myslot = lds_slot[wave];

    float4 buf[8];   // one half-tile payload: 8 instrs x (2 rows x 512B)

    // instr i reads rows 2i,2i+1 bytes [h*512, h*512+512) in pure lane order
#define LOADH(T, H) do {                                                      \
    const float* p_ = wtgt + (size_t)(T) * (16 * D_) + (H) * 128              \
                           + lrow * D_ + lcol;                                \
    _Pragma("unroll")                                                         \
    for (int i = 0; i < 8; ++i) buf[i] = *(const float4*)(p_ + i * 2 * D_);   \
} while (0)

    // slot[row][k-within-half]; row = 2i+lrow, col = lcol
#define STOREH() do {                                                         \
    short* d_ = myslot + lrow * SLS + lcol;                                   \
    _Pragma("unroll")                                                         \
    for (int i = 0; i < 8; ++i) *(bf16x4*)(d_ + i * 2 * SLS) = cvt4(buf[i]);  \
} while (0)

    LOADH(0, 0);   // prime: first half-tile in flight across the prologue

    // --- stage W2: fp32 [D][U] -> bf16 LDS [u][d], b128 writes ---
    {
        const int u  = tid & (U_ - 1);
        const int d0 = (tid >> 7) << 5;      // 8 groups x 32 d
        #pragma unroll
        for (int w = 0; w < 4; ++w) {
            const int dd = d0 + w * 8;
            bf16x8 v;
            #pragma unroll
            for (int i = 0; i < 8; ++i)
                v[i] = f2bf(W2[(size_t)(dd + i) * U_ + u]);
            *(bf16x8*)&lds_w2[u * W2S + dd] = v;
        }
    }

    // --- s[u] = (source[b] @ W1)[u], 8-way D split over 1024 threads ---
    {
        const float* src = source + b * D_;
        const int u    = tid & (U_ - 1);
        const int part = tid >> 7;           // 0..7, 32 d each
        float acc = 0.f;
        #pragma unroll 8
        for (int d = part * 32; d < part * 32 + 32; ++d)
            acc = fmaf(src[d], W1[(size_t)d * U_ + u], acc);
        lds_red[tid] = acc;
    }
    __syncthreads();
    if (tid < U_) {
        float s = 0.f;
        #pragma unroll
        for (int p = 0; p < 8; ++p) s += lds_red[tid + 128 * p];
        lds_sa[tid] = make_float2(s, attn[tid]);
    }
    __syncthreads();
    // ---- no block-wide synchronization below this line ----

    f32x4 acc[8];
    #pragma unroll
    for (int j = 0; j < 8; ++j) acc[j] = (f32x4){0.f, 0.f, 0.f, 0.f};

    // A-op = W2 frag (u-dim), B-op = target frag (rows). Wave-private slot.
#define COMPH(H) do {                                                         \
    _Pragma("unroll")                                                         \
    for (int kk = 0; kk < 4; ++kk) {                                          \
        bf16x8 af = *(const bf16x8*)(myslot + c * SLS + kk * 32 + g * 8);     \
        _Pragma("unroll")                                                     \
        for (int j = 0; j < 8; ++j) {                                         \
            bf16x8 wf = *(const bf16x8*)                                      \
                &lds_w2[(16 * j + c) * W2S + (H) * 128 + kk * 32 + g * 8];    \
            acc[j] = __builtin_amdgcn_mfma_f32_16x16x32_bf16(wf, af, acc[j], 0, 0, 0); \
        }                                                                     \
    }                                                                         \
} while (0)

    // lane (c,g) holds t[row=c][u=16j+4g+r] in acc[j][r]
#define EPI(T) do {                                                           \
    float sc = 0.f;                                                           \
    _Pragma("unroll")                                                         \
    for (int j = 0; j < 8; ++j) {                                             \
        const float4 sa01 = *(const float4*)&lds_sa[16 * j + 4 * g];          \
        const float4 sa23 = *(const float4*)&lds_sa[16 * j + 4 * g + 2];      \
        sc += fast_tanh(acc[j][0] + sa01.x) * sa01.y;                         \
        sc += fast_tanh(acc[j][1] + sa01.z) * sa01.w;                         \
        sc += fast_tanh(acc[j][2] + sa23.x) * sa23.y;                         \
        sc += fast_tanh(acc[j][3] + sa23.z) * sa23.w;                         \
        acc[j] = (f32x4){0.f, 0.f, 0.f, 0.f};                                 \
    }                                                                         \
    sc += __shfl_xor(sc, 16);                                                 \
    sc += __shfl_xor(sc, 32);                                                 \
    if (lane < 16) wout[(T) * 16 + lane] = sc;                                \
} while (0)

    // 8 tiles x 2 k-halves per wave; single payload buffer, loads for the next
    // half issued before COMP so HBM latency hides under the MFMA/LDS phase.
    for (int t = 0; t < 8; ++t) {
        STOREH();                 // (t, h0) -> slot   (waits its loads)
        LOADH(t, 1);              // issue (t, h1)
        COMPH(0);
        STOREH();                 // (t, h1) -> slot
        if (t < 7) LOADH(t + 1, 0);
        COMPH(1);
        EPI(t);
    }

#undef LOADH
#undef STOREH
#undef COMPH
#undef EPI
}

extern "C" void kernel_launch(void* const* d_in, const int* in_sizes, int n_in,
                              void* d_out, int out_size, void* d_ws, size_t ws_size,
                              hipStream_t stream) {
    const float* target = (const float*)d_in[0];
    const float* source = (const float*)d_in[1];
    const float* W1     = (const float*)d_in[2];
    const float* W2     = (const float*)d_in[3];
    const float* attn   = (const float*)d_in[4];
    float* out = (float*)d_out;

    dim3 grid(B_ * (T_ / 2048));   // 256 blocks = 1 per CU
    dim3 block(1024);
    hipLaunchKernelGGL(additive_attn_kernel, grid, block, 0, stream,
                       target, source, W1, W2, attn, out);
}

// Round 8
// 136.312 us; speedup vs baseline: 3.8167x; 3.8167x over previous
//
#include <hip/hip_runtime.h>
#include <hip/hip_bf16.h>

// scores[b,t] = sum_u tanh((source@W1)[b,u] + (target@W2)[b,t,u]) * a[u]
// B=64 T=8192 D=256 U=128. Memory-bound: 537MB target read; ~86us floor at 6.3TB/s.
// Round 8: fit the live set in 64 VGPRs. R7 exposed the allocator pinning VGPR=64
// (even with waves_per_eu(4,4)) => R2-R5 were silently spilling (live ~85 regs);
// their ~5TB/s "ceiling" was likely full-BW on ideal+scratch bytes. Now: wave pairs
// split u (acc 16 regs), single 16-reg payload buffer with cvt->issue-next->MFMA
// ordering, peak live ~56. Pair waves load identical addresses (2nd is an L2 hit;
// HBM unchanged). u-halves combine via 1KB LDS + 1 barrier per 64-row sweep.

#define B_ 64
#define T_ 8192
#define D_ 256
#define U_ 128
#define LDSW 264   // W2 LDS stride (bf16): 528B rows -> conflict-free b128 frag reads

typedef __attribute__((ext_vector_type(8))) short bf16x8;
typedef __attribute__((ext_vector_type(4))) float f32x4;

__device__ __forceinline__ short f2bf(float f) {
    unsigned u = __builtin_bit_cast(unsigned, f);
    u += 0x7fffu + ((u >> 16) & 1u);   // RTNE
    return (short)(u >> 16);
}

__device__ __forceinline__ float fast_tanh(float x) {
    float e = __expf(2.0f * x);
    return 1.0f - 2.0f * __builtin_amdgcn_rcpf(e + 1.0f);
}

__device__ __forceinline__ bf16x8 cvt8(const float4& a, const float4& b) {
    union { __hip_bfloat162 h[4]; bf16x8 v; } u;
    u.h[0] = __float22bfloat162_rn(make_float2(a.x, a.y));
    u.h[1] = __float22bfloat162_rn(make_float2(a.z, a.w));
    u.h[2] = __float22bfloat162_rn(make_float2(b.x, b.y));
    u.h[3] = __float22bfloat162_rn(make_float2(b.z, b.w));
    return u.v;
}

__global__ __launch_bounds__(512) void additive_attn_kernel(
        const float* __restrict__ target,
        const float* __restrict__ source,
        const float* __restrict__ W1,
        const float* __restrict__ W2,
        const float* __restrict__ attn,
        float* __restrict__ out) {
    __shared__ __attribute__((aligned(16))) short lds_w2[U_ * LDSW];  // 67.6 KB
    __shared__ float  lds_red[512];
    __shared__ __attribute__((aligned(16))) float2 lds_sa[U_];        // {s_u, a_u}
    __shared__ float  lds_part[2][2][4][16];  // [sweep parity][uh][rg][row]

    const int tid  = threadIdx.x;
    const int bx   = blockIdx.x;
    const int b    = bx >> 3;            // 8 blocks per batch element
    const int tb   = (bx & 7) << 10;     // 1024 rows per block

    const int lane = tid & 63;
    const int wave = tid >> 6;           // 0..7
    const int rg   = wave >> 1;          // row-group within sweep (4 x 16 rows)
    const int uh   = wave & 1;           // u-half: [uh*64, uh*64+64)
    const int c    = lane & 15;
    const int g    = lane >> 4;

    const float* tgt  = target + ((size_t)b * T_ + tb) * D_;
    float*       outp = out + (size_t)b * T_ + tb;
    const float* Abase = tgt + (size_t)(rg * 16 + c) * D_ + g * 8;
    const short* w2base = &lds_w2[(64 * uh + c) * LDSW];

    float4 x0, x1, x2, x3;   // single payload buffer: one k-quarter, 16 rows

    // quarter Q of sweep S: rows S*64+rg*16+{c}, k = Q*64 + g*8 + [0,8) and +32
#define LOADQ(S, Q) do {                                                      \
    const float* p_ = Abase + (size_t)(S) * (64 * D_) + (Q) * 64;             \
    x0 = *(const float4*)(p_);      x1 = *(const float4*)(p_ + 4);            \
    x2 = *(const float4*)(p_ + 32); x3 = *(const float4*)(p_ + 36);           \
} while (0)

    LOADQ(0, 0);   // in flight across the whole prologue

    // --- stage W2: fp32 [D][U] -> bf16 LDS [u][d], b128 writes ---
    {
        const int u    = tid & (U_ - 1);
        const int dblk = (tid >> 7) << 6;    // 0,64,128,192
        #pragma unroll
        for (int w = 0; w < 8; ++w) {
            const int d0 = dblk + w * 8;
            bf16x8 v;
            #pragma unroll
            for (int i = 0; i < 8; ++i)
                v[i] = f2bf(W2[(size_t)(d0 + i) * U_ + u]);
            *(bf16x8*)&lds_w2[u * LDSW + d0] = v;
        }
    }

    // --- s[u] = (source[b] @ W1)[u], 4-way D split ---
    {
        const float* src = source + b * D_;
        const int u    = tid & (U_ - 1);
        const int part = tid >> 7;
        float acc1 = 0.f;
        #pragma unroll 8
        for (int d = part * 64; d < part * 64 + 64; ++d)
            acc1 = fmaf(src[d], W1[(size_t)d * U_ + u], acc1);
        lds_red[tid] = acc1;
    }
    __syncthreads();
    if (tid < U_)
        lds_sa[tid] = make_float2(
            lds_red[tid] + lds_red[tid + 128] + lds_red[tid + 256] + lds_red[tid + 384],
            attn[tid]);
    __syncthreads();

    f32x4 acc[4];
    #pragma unroll
    for (int j = 0; j < 4; ++j) acc[j] = (f32x4){0.f, 0.f, 0.f, 0.f};

    // MFMA for quarter Q: A-op = W2 frag (m = u-in-tile), B-op = target (n = row c)
#define MFMAQ(AF0, AF1, Q) do {                                               \
    const int kb_ = (Q) * 64 + g * 8;                                         \
    _Pragma("unroll")                                                         \
    for (int j = 0; j < 4; ++j) {                                             \
        bf16x8 w0 = *(const bf16x8*)(w2base + j * 16 * LDSW + kb_);           \
        acc[j] = __builtin_amdgcn_mfma_f32_16x16x32_bf16(w0, AF0, acc[j], 0, 0, 0); \
        bf16x8 w1 = *(const bf16x8*)(w2base + j * 16 * LDSW + kb_ + 32);      \
        acc[j] = __builtin_amdgcn_mfma_f32_16x16x32_bf16(w1, AF1, acc[j], 0, 0, 0); \
    }                                                                         \
} while (0)

    // one quarter: convert payload (frees buffer), issue next loads, then MFMA
#define STEP(S, Q) do {                                                       \
    bf16x8 af0 = cvt8(x0, x1);                                                \
    bf16x8 af1 = cvt8(x2, x3);                                                \
    if (!((S) == 15 && (Q) == 3)) {                                           \
        const int nx_ = (S) * 4 + (Q) + 1;                                    \
        LOADQ(nx_ >> 2, nx_ & 3);                                             \
    }                                                                         \
    MFMAQ(af0, af1, Q);                                                       \
} while (0)

    for (int s = 0; s < 16; ++s) {
        STEP(s, 0); STEP(s, 1); STEP(s, 2); STEP(s, 3);

        // epilogue: lane (c,g) holds t[row=c][u=64uh+16j+4g+r] in acc[j][r]
        float sc = 0.f;
        #pragma unroll
        for (int j = 0; j < 4; ++j) {
            const float4 sa01 = *(const float4*)&lds_sa[uh * 64 + 16 * j + 4 * g];
            const float4 sa23 = *(const float4*)&lds_sa[uh * 64 + 16 * j + 4 * g + 2];
            sc += fast_tanh(acc[j][0] + sa01.x) * sa01.y;
            sc += fast_tanh(acc[j][1] + sa01.z) * sa01.w;
            sc += fast_tanh(acc[j][2] + sa23.x) * sa23.y;
            sc += fast_tanh(acc[j][3] + sa23.z) * sa23.w;
            acc[j] = (f32x4){0.f, 0.f, 0.f, 0.f};
        }
        sc += __shfl_xor(sc, 16);
        sc += __shfl_xor(sc, 32);
        if (lane < 16) lds_part[s & 1][uh][rg][lane] = sc;
        __syncthreads();
        if (tid < 64)
            outp[s * 64 + tid] = lds_part[s & 1][0][tid >> 4][tid & 15]
                               + lds_part[s & 1][1][tid >> 4][tid & 15];
    }

#undef LOADQ
#undef MFMAQ
#undef STEP
}

extern "C" void kernel_launch(void* const* d_in, const int* in_sizes, int n_in,
                              void* d_out, int out_size, void* d_ws, size_t ws_size,
                              hipStream_t stream) {
    const float* target = (const float*)d_in[0];
    const float* source = (const float*)d_in[1];
    const float* W1     = (const float*)d_in[2];
    const float* W2     = (const float*)d_in[3];
    const float* attn   = (const float*)d_in[4];
    float* out = (float*)d_out;

    dim3 grid(B_ * (T_ / 1024));   // 512 blocks = 2 per CU
    dim3 block(512);
    hipLaunchKernelGGL(additive_attn_kernel, grid, block, 0, stream,
                       target, source, W1, W2, attn, out);
}

// Round 9
// 115.452 us; speedup vs baseline: 4.5063x; 1.1807x over previous
//
#include <hip/hip_runtime.h>
#include <hip/hip_bf16.h>

// scores[b,t] = sum_u tanh((source@W1)[b,u] + (target@W2)[b,t,u]) * a[u]
// B=64 T=8192 D=256 U=128. Memory-bound: 537MB target read; ~86us floor at 6.3TB/s.
// Round 9: TRUE row-linear loads (the only pattern measured at 6.6+ TB/s on this
// chip). Each wave loads 2 complete 1KB rows per tile as single dwordx4 instrs
// (lane l <-> bytes 16l), cvt -> swizzled bf16 LDS tile (16 rows x 512B, dbuf).
// W2 frags live in REGISTERS (wave owns 16 u -> 8 x bf16x8 = 32 VGPR), so LDS is
// tiny (20KB) and the K-loop is 8 x (ds_read_b128 + MFMA). 2-tile-ahead payload
// pipeline; one barrier/tile; NO global stores in the loop (outputs held in 2
// regs/thread, written at end) so barriers drain lgkmcnt only and register loads
// stay in flight across them.

#define B_ 64
#define T_ 8192
#define D_ 256
#define U_ 128
#define TM 16        // rows per tile
#define NT 64        // tiles per block (1024 rows)

typedef __attribute__((ext_vector_type(8))) short bf16x8;
typedef __attribute__((ext_vector_type(4))) short bf16x4;
typedef __attribute__((ext_vector_type(4))) float f32x4;

__device__ __forceinline__ short f2bf(float f) {
    unsigned u = __builtin_bit_cast(unsigned, f);
    u += 0x7fffu + ((u >> 16) & 1u);   // RTNE
    return (short)(u >> 16);
}

__device__ __forceinline__ float fast_tanh(float x) {
    float e = __expf(2.0f * x);
    return 1.0f - 2.0f * __builtin_amdgcn_rcpf(e + 1.0f);
}

__device__ __forceinline__ bf16x4 cvt4(const float4& a) {
    union { __hip_bfloat162 h[2]; bf16x4 v; } u;
    u.h[0] = __float22bfloat162_rn(make_float2(a.x, a.y));
    u.h[1] = __float22bfloat162_rn(make_float2(a.z, a.w));
    return u.v;
}

__global__ __launch_bounds__(512) void additive_attn_kernel(
        const float* __restrict__ target,
        const float* __restrict__ source,
        const float* __restrict__ W1,
        const float* __restrict__ W2,
        const float* __restrict__ attn,
        float* __restrict__ out) {
    // bf16 target tile, double-buffered; rows are 512B, XOR-swizzled in 16B units
    __shared__ __attribute__((aligned(16))) short lds_buf[2][TM * 256];  // 16 KB
    __shared__ float  lds_red[512];
    __shared__ __attribute__((aligned(16))) float2 lds_sa[U_];           // {s_u,a_u}
    __shared__ float  lds_part[2][8][TM];

    const int tid  = threadIdx.x;
    const int bx   = blockIdx.x;
    const int b    = bx >> 3;            // 8 blocks per batch element
    const int tb   = (bx & 7) << 10;     // 1024 rows per block

    const int lane = tid & 63;
    const int wave = tid >> 6;           // 0..7 = u-slice owner (u in [wave*16,+16))
    const int c    = lane & 15;
    const int g    = lane >> 4;

    const float* tgt  = target + ((size_t)b * T_ + tb) * D_;
    float*       outp = out + (size_t)b * T_ + tb;

    float4 pA0, pA1, pB0, pB1;   // 2 payload sets x 2 full rows

    // one instruction = one full 1KB row, lane l reads bytes [16l, 16l+16)
#define LOADT(X0, X1, TT) do {                                                \
    const float* p_ = tgt + ((size_t)(TT) * TM + 2 * wave) * D_ + lane * 4;   \
    X0 = *(const float4*)(p_);                                                \
    X1 = *(const float4*)(p_ + D_);                                           \
} while (0)

    // row r, lane l: logical bytes [8l,8l+8) -> phys byte (8l)^((r&7)<<4)
#define STORET(BP, X0, X1) do {                                               \
    const int r0_ = 2 * wave;                                                 \
    char* base_ = (char*)&lds_buf[BP][0];                                     \
    *(bf16x4*)(base_ + r0_ * 512 + ((8 * lane) ^ ((r0_ & 7) << 4))) = cvt4(X0); \
    *(bf16x4*)(base_ + (r0_ + 1) * 512 + ((8 * lane) ^ (((r0_ + 1) & 7) << 4))) = cvt4(X1); \
} while (0)

    LOADT(pA0, pA1, 0);   // tiles 0,1 in flight across the whole prologue
    LOADT(pB0, pB1, 1);

    // --- W2 frags -> registers: wf[kk][e] = W2bf[k=kk*32+g*8+e][u=wave*16+c] ---
    bf16x8 wf[8];
    {
        const float* wbase = W2 + (size_t)(g * 8) * U_ + wave * 16 + c;
        #pragma unroll
        for (int kk = 0; kk < 8; ++kk) {
            bf16x8 v;
            #pragma unroll
            for (int e = 0; e < 8; ++e)
                v[e] = f2bf(wbase[(size_t)(kk * 32 + e) * U_]);
            wf[kk] = v;
        }
    }

    STORET(0, pA0, pA1);   // tile 0 -> buf0 (visibility via prologue barriers)

    // --- s[u] = (source[b] @ W1)[u], 4-way D split ---
    {
        const float* src = source + b * D_;
        const int u    = tid & (U_ - 1);
        const int part = tid >> 7;
        float a1 = 0.f;
        #pragma unroll 8
        for (int d = part * 64; d < part * 64 + 64; ++d)
            a1 = fmaf(src[d], W1[(size_t)d * U_ + u], a1);
        lds_red[tid] = a1;
    }
    __syncthreads();
    if (tid < U_)
        lds_sa[tid] = make_float2(
            lds_red[tid] + lds_red[tid + 128] + lds_red[tid + 256] + lds_red[tid + 384],
            attn[tid]);
    __syncthreads();

    // hoist per-lane epilogue constants: u = wave*16 + 4g + r
    const float4 sa01 = *(const float4*)&lds_sa[wave * 16 + 4 * g];
    const float4 sa23 = *(const float4*)&lds_sa[wave * 16 + 4 * g + 2];

    f32x4 acc = (f32x4){0.f, 0.f, 0.f, 0.f};
    float osum0 = 0.f, osum1 = 0.f;

    for (int t = 0; t < NT; ++t) {
        // A: refill payload set P[t&1] with tile t+2 (issue early, in flight
        //    across this iter's barrier -- no stores pending, so no vmcnt drain)
        if (t < NT - 2) {
            if (t & 1) LOADT(pB0, pB1, t + 2);
            else       LOADT(pA0, pA1, t + 2);
        }

        // B: compute tile t from buf[t&1]
        {
            const char* bp = (const char*)&lds_buf[t & 1][0] + c * 512;
            #pragma unroll
            for (int kk = 0; kk < 8; ++kk) {
                bf16x8 af = *(const bf16x8*)(bp + ((kk * 64 + g * 16) ^ ((c & 7) << 4)));
                acc = __builtin_amdgcn_mfma_f32_16x16x32_bf16(wf[kk], af, acc, 0, 0, 0);
            }
        }

        // D: stage tile t+1 (payload arrived ~1.5 iters ago) into buf[(t+1)&1]
        if (t < NT - 1) {
            if ((t + 1) & 1) STORET(1, pB0, pB1);
            else             STORET(0, pA0, pA1);
        }

        // EPI: lane (c,g) holds t[row=c][u=wave*16+4g+r] in acc[r]
        {
            float sc = fast_tanh(acc[0] + sa01.x) * sa01.y
                     + fast_tanh(acc[1] + sa01.z) * sa01.w
                     + fast_tanh(acc[2] + sa23.x) * sa23.y
                     + fast_tanh(acc[3] + sa23.z) * sa23.w;
            acc = (f32x4){0.f, 0.f, 0.f, 0.f};
            sc += __shfl_xor(sc, 16);
            sc += __shfl_xor(sc, 32);
            if (lane < 16) lds_part[t & 1][wave][lane] = sc;
        }

        // combine tile t-1's 8 u-slice partials (16-thread group (t-1)&31)
        if (t > 0 && (tid >> 4) == ((t - 1) & 31)) {
            float v = 0.f;
            #pragma unroll
            for (int w = 0; w < 8; ++w) v += lds_part[(t - 1) & 1][w][tid & 15];
            if (t <= 32) osum0 = v; else osum1 = v;
        }

        __syncthreads();
    }

    // final tile's partials (t=63, parity 1, group 31)
    if ((tid >> 4) == 31) {
        float v = 0.f;
        #pragma unroll
        for (int w = 0; w < 8; ++w) v += lds_part[1][w][tid & 15];
        osum1 = v;
    }

    // outputs: group gq handled tiles gq and gq+32; row = tid&15
    outp[tid]       = osum0;
    outp[tid + 512] = osum1;

#undef LOADT
#undef STORET
}

extern "C" void kernel_launch(void* const* d_in, const int* in_sizes, int n_in,
                              void* d_out, int out_size, void* d_ws, size_t ws_size,
                              hipStream_t stream) {
    const float* target = (const float*)d_in[0];
    const float* source = (const float*)d_in[1];
    const float* W1     = (const float*)d_in[2];
    const float* W2     = (const float*)d_in[3];
    const float* attn   = (const float*)d_in[4];
    float* out = (float*)d_out;

    dim3 grid(B_ * (T_ / 1024));   // 512 blocks = 2 per CU
    dim3 block(512);
    hipLaunchKernelGGL(additive_attn_kernel, grid, block, 0, stream,
                       target, source, W1, W2, attn, out);
}